// Round 5
// baseline (331.194 us; speedup 1.0000x reference)
//
#include <hip/hip_runtime.h>
#include <hip/hip_bf16.h>
#include <cmath>

// ---------------------------------------------------------------------------
// GCN: out = tanh(relu(relu(relu(relu(P(P(P(P(xW1+..)..) .. ))Wf1+bf1)Wf2+bf2
// P = D^-1/2 (A+I) D^-1/2 via bucketed CSR gather-sum, no float atomics.
// R14: group-per-node register agg (345.7us). R15: fixed-cap buckets + agg
// fused into GEMM A-staging (342.4us). R16: L4 W from global + U=8 gather
// (319.9us) -- but L4 occupancy only 31.6%: grid 1563 = 6.1 blocks/CU total,
// no refill, barrier ties waves to slowest gather.
// R17: TM=32 for fused L3/L4 -> 3125 blocks (2x grid, refill queue, halved
// barrier-imbalance scope). L3 gather CPL 8->4 so all 64 groups stay busy
// with 32 rows. L4 LDS ~9KB. L2 stays TM=64 (not the bottleneck).
// ---------------------------------------------------------------------------

#define NBUCK 391              // ceil(100000/256) 256-node buckets
#define PREB  391              // ceil(E/4096) edge-phase blocks
#define BCAP  5120             // edges per bucket capacity (mean 4096, 16s)

typedef __attribute__((ext_vector_type(8))) unsigned short ushort8v;

__device__ __forceinline__ unsigned short f_to_bf(float v) {
    unsigned u = __float_as_uint(v);
    return (unsigned short)((u + 0x7FFF + ((u >> 16) & 1)) >> 16);   // RTN-even
}
__device__ __forceinline__ float bf_to_f(unsigned short v) {
    return __uint_as_float((unsigned)v << 16);
}

template<int VE> struct BFV;
template<> struct BFV<4> {
    using T = ushort4;
    __device__ static inline void unpack(const T& u, float* f) {
        f[0] = bf_to_f(u.x); f[1] = bf_to_f(u.y);
        f[2] = bf_to_f(u.z); f[3] = bf_to_f(u.w);
    }
};
template<> struct BFV<8> {
    using T = ushort8v;
    __device__ static inline void unpack(const T& u, float* f) {
#pragma unroll
        for (int j = 0; j < 8; j++) f[j] = bf_to_f(u[j]);
    }
};

__device__ __forceinline__ ushort8v pack8(const float* f) {
    ushort8v u;
#pragma unroll
    for (int j = 0; j < 8; j++) u[j] = f_to_bf(f[j]);
    return u;
}

__global__ void init_cursor_kernel(int* __restrict__ cur) {
    int i = blockIdx.x * 256 + threadIdx.x;
    if (i < NBUCK) cur[i] = i * BCAP;
}

// Phase A: scatter packed edges into fixed-capacity bucket regions.
// payload = (dst&255)<<17 | src. cursors pre-init'ed to b*BCAP.
__global__ __launch_bounds__(256) void place_kernel(
        const int* __restrict__ src, const int* __restrict__ dst,
        int* __restrict__ bucket_cursor, int* __restrict__ csr_tmp, int E) {
    __shared__ int hist[NBUCK];
    const int t = threadIdx.x;
    for (int i = t; i < NBUCK; i += 256) hist[i] = 0;
    __syncthreads();
    const int base = blockIdx.x * 4096;
    int pay[16], rb[16];
#pragma unroll
    for (int j = 0; j < 16; j++) {
        int e = base + j * 256 + t;
        if (e < E) {
            int d = dst[e];
            int b = d >> 8;
            int r = atomicAdd(&hist[b], 1);       // r < 4096 (12 bits)
            pay[j] = ((d & 255) << 17) | src[e];
            rb[j] = (r << 9) | b;                 // b < 512 (9 bits)
        } else rb[j] = -1;
    }
    __syncthreads();
    for (int i = t; i < NBUCK; i += 256) {
        int h = hist[i];
        hist[i] = h ? atomicAdd(&bucket_cursor[i], h) : 0;
    }
    __syncthreads();
#pragma unroll
    for (int j = 0; j < 16; j++) {
        if (rb[j] >= 0) {
            int b = rb[j] & 511;
            int r = rb[j] >> 9;
            csr_tmp[hist[b] + r] = pay[j];
        }
    }
}

// Phase B: one block per bucket -> per-node CSR (row_ptr + deg + csr_src,
// padded-bucket layout) + dinv.
__global__ __launch_bounds__(256) void bsort_kernel(
        const int* __restrict__ bucket_cursor, const int* __restrict__ csr_tmp,
        int* __restrict__ row_ptr, int* __restrict__ csr_src,
        int* __restrict__ degp, float* __restrict__ dinv, int N) {
    __shared__ int c[256], s[256], cur[256];
    const int b = blockIdx.x;
    const int t = threadIdx.x;
    const int start = b * BCAP;
    const int end = bucket_cursor[b];            // absolute fill end
    c[t] = 0;
    __syncthreads();
    for (int e = start + t; e < end; e += 256)
        atomicAdd(&c[csr_tmp[e] >> 17], 1);
    __syncthreads();
    int v = c[t];
    s[t] = v; __syncthreads();
    for (int off = 1; off < 256; off <<= 1) {
        int x = (t >= off) ? s[t - off] : 0;
        __syncthreads();
        s[t] += x;
        __syncthreads();
    }
    int excl = s[t] - v;
    int node = (b << 8) + t;
    if (node < N) {
        row_ptr[node] = start + excl;
        degp[node] = v;
        dinv[node] = rsqrtf((float)v + 1.0f);
    }
    cur[t] = start + excl;
    __syncthreads();
    for (int e = start + t; e < end; e += 256) {
        int p = csr_tmp[e];
        int pos = atomicAdd(&cur[p >> 17], 1);
        csr_src[pos] = p & 0x1FFFF;
    }
}

// --- group-per-node bf16 aggregation over PRESCALED input zs = dinv*z ------
// Used standalone only for L1 (bias+relu, prescale-out). G = F/8 lanes own
// one node; 8 channels/lane in registers, U=4 gathers in flight.
template<int F, bool L1MODE, bool PRESCALE_OUT>
__global__ __launch_bounds__(256) void agg_gpn_kernel(
        const unsigned short* __restrict__ z, const int* __restrict__ row_ptr,
        const int* __restrict__ degp, const int* __restrict__ csr_src,
        const float* __restrict__ dinv, const float* __restrict__ bias,
        unsigned short* __restrict__ out, int N) {
    constexpr int G  = F / 8;          // lanes per node
    constexpr int NPB = 256 / G;       // nodes per block
    const int t = threadIdx.x;
    const int c0 = (t % G) * 8;
    const int node = blockIdx.x * NPB + t / G;
    if (node >= N) return;             // group-uniform exit, no barriers below
    const int start = row_ptr[node];
    const int end   = start + degp[node];
    float acc[8];
#pragma unroll
    for (int j = 0; j < 8; j++) acc[j] = 0.f;
    int e = start;
    while (e + 3 < end) {              // U=4: 4 independent gathers in flight
        int s0 = csr_src[e];
        int s1 = csr_src[e + 1];
        int s2 = csr_src[e + 2];
        int s3 = csr_src[e + 3];
        ushort8v u0 = *(const ushort8v*)&z[(size_t)s0 * F + c0];
        ushort8v u1 = *(const ushort8v*)&z[(size_t)s1 * F + c0];
        ushort8v u2 = *(const ushort8v*)&z[(size_t)s2 * F + c0];
        ushort8v u3 = *(const ushort8v*)&z[(size_t)s3 * F + c0];
        float f0[8], f1[8], f2[8], f3[8];
        BFV<8>::unpack(u0, f0); BFV<8>::unpack(u1, f1);
        BFV<8>::unpack(u2, f2); BFV<8>::unpack(u3, f3);
#pragma unroll
        for (int j = 0; j < 8; j++) acc[j] += (f0[j] + f1[j]) + (f2[j] + f3[j]);
        e += 4;
    }
    if (e + 1 < end) {                 // U=2
        int s0 = csr_src[e];
        int s1 = csr_src[e + 1];
        ushort8v u0 = *(const ushort8v*)&z[(size_t)s0 * F + c0];
        ushort8v u1 = *(const ushort8v*)&z[(size_t)s1 * F + c0];
        float f0[8], f1[8];
        BFV<8>::unpack(u0, f0); BFV<8>::unpack(u1, f1);
#pragma unroll
        for (int j = 0; j < 8; j++) acc[j] += f0[j] + f1[j];
        e += 2;
    }
    if (e < end) {                     // tail
        int s0 = csr_src[e];
        ushort8v u0 = *(const ushort8v*)&z[(size_t)s0 * F + c0];
        float f0[8];
        BFV<8>::unpack(u0, f0);
#pragma unroll
        for (int j = 0; j < 8; j++) acc[j] += f0[j];
    }
    const float di = dinv[node];
    ushort8v us = *(const ushort8v*)&z[(size_t)node * F + c0];
    float fs[8], r[8];
    BFV<8>::unpack(us, fs);
#pragma unroll
    for (int j = 0; j < 8; j++) r[j] = di * (acc[j] + fs[j]);
    if (L1MODE) {
#pragma unroll
        for (int j = 0; j < 8; j++) r[j] = fmaxf(r[j] + bias[c0 + j], 0.f);
    }
    if (PRESCALE_OUT) {
#pragma unroll
        for (int j = 0; j < 8; j++) r[j] *= di;
    }
    *(ushort8v*)&out[(size_t)node * F + c0] = pack8(r);
}

// --- fused agg+GEMM: As[r][k] = dinv*(sum_e z[src][k] + z[r][k]); then
// out = relu(As @ W + b) [* dinv if PRESCALE], bf16 out, width MB*CS.
// CPL channels per lane during gather; CS col-splits in-register. WLDS=false:
// read W from global (L1/L2-resident). U = gathers in flight per lane.
// TM = (256/CG)*RT; TM=32 doubles the grid for occupancy/refill.
template<int K, int MB, int RT, int CS, int CPL, bool PRESCALE, bool WLDS, int U>
__global__ __launch_bounds__(256) void gemm_agg_kernel(
        const unsigned short* __restrict__ z, const int* __restrict__ row_ptr,
        const int* __restrict__ degp, const int* __restrict__ csr_src,
        const float* __restrict__ dinv, const float* __restrict__ W,
        const float* __restrict__ bias, unsigned short* __restrict__ out, int N) {
    constexpr int CG = MB / 4;
    constexpr int TM = (256 / CG) * RT;
    constexpr int KP = K + 4;            // 2-way bank alias on As reads (free)
    constexpr int MBT = MB * CS;
    static_assert(TM == 64 || TM == 32, "tile rows");
    __shared__ float As[TM * KP];
    __shared__ float Ws[WLDS ? K * MBT : 4];
    __shared__ float bs[MBT];
    const int t = threadIdx.x;
    const int base = blockIdx.x * TM;

    {   // ---- gather-staged A (the fused aggregation) ----
        using VT = typename BFV<CPL>::T;
        constexpr int G = K / CPL;       // lanes per node
        constexpr int NPB = 256 / G;     // nodes in flight
        const int gg = t / G;
        const int ac0 = (t % G) * CPL;
        for (int r = gg; r < TM; r += NPB) {
            const int node = base + r;
            float res[CPL];
            if (node < N) {
                const int start = row_ptr[node];
                const int end = start + degp[node];
                float acc[CPL];
#pragma unroll
                for (int j = 0; j < CPL; j++) acc[j] = 0.f;
                int e = start;
                if (U == 8) {
                    while (e + 7 < end) {    // U=8 gathers in flight
                        int ss[8];
#pragma unroll
                        for (int u = 0; u < 8; u++) ss[u] = csr_src[e + u];
                        VT uu[8];
#pragma unroll
                        for (int u = 0; u < 8; u++)
                            uu[u] = *(const VT*)&z[(size_t)ss[u] * K + ac0];
#pragma unroll
                        for (int u = 0; u < 8; u++) {
                            float f[CPL];
                            BFV<CPL>::unpack(uu[u], f);
#pragma unroll
                            for (int j = 0; j < CPL; j++) acc[j] += f[j];
                        }
                        e += 8;
                    }
                }
                while (e + 3 < end) {    // U=4 gathers in flight
                    int s0 = csr_src[e];
                    int s1 = csr_src[e + 1];
                    int s2 = csr_src[e + 2];
                    int s3 = csr_src[e + 3];
                    VT u0 = *(const VT*)&z[(size_t)s0 * K + ac0];
                    VT u1 = *(const VT*)&z[(size_t)s1 * K + ac0];
                    VT u2 = *(const VT*)&z[(size_t)s2 * K + ac0];
                    VT u3 = *(const VT*)&z[(size_t)s3 * K + ac0];
                    float f0[CPL], f1[CPL], f2[CPL], f3[CPL];
                    BFV<CPL>::unpack(u0, f0); BFV<CPL>::unpack(u1, f1);
                    BFV<CPL>::unpack(u2, f2); BFV<CPL>::unpack(u3, f3);
#pragma unroll
                    for (int j = 0; j < CPL; j++)
                        acc[j] += (f0[j] + f1[j]) + (f2[j] + f3[j]);
                    e += 4;
                }
                if (e + 1 < end) {       // U=2
                    int s0 = csr_src[e];
                    int s1 = csr_src[e + 1];
                    VT u0 = *(const VT*)&z[(size_t)s0 * K + ac0];
                    VT u1 = *(const VT*)&z[(size_t)s1 * K + ac0];
                    float f0[CPL], f1[CPL];
                    BFV<CPL>::unpack(u0, f0); BFV<CPL>::unpack(u1, f1);
#pragma unroll
                    for (int j = 0; j < CPL; j++) acc[j] += f0[j] + f1[j];
                    e += 2;
                }
                if (e < end) {           // tail
                    int s0 = csr_src[e];
                    VT u0 = *(const VT*)&z[(size_t)s0 * K + ac0];
                    float f0[CPL];
                    BFV<CPL>::unpack(u0, f0);
#pragma unroll
                    for (int j = 0; j < CPL; j++) acc[j] += f0[j];
                }
                const float di = dinv[node];
                VT us = *(const VT*)&z[(size_t)node * K + ac0];
                float fs[CPL];
                BFV<CPL>::unpack(us, fs);
#pragma unroll
                for (int j = 0; j < CPL; j++) res[j] = di * (acc[j] + fs[j]);
            } else {
#pragma unroll
                for (int j = 0; j < CPL; j++) res[j] = 0.f;
            }
#pragma unroll
            for (int j = 0; j < CPL; j++) As[r * KP + ac0 + j] = res[j];
        }
    }
    // ---- W (optional) + bias staging ----
    if (WLDS) {
        constexpr int MD4 = MBT / 4;
        for (int idx = t; idx < K * MD4; idx += 256) {
            int k = idx / MD4, c4 = idx % MD4;
            *(float4*)&Ws[k * MBT + c4 * 4] = *(const float4*)&W[(size_t)k * MBT + c4 * 4];
        }
    }
    if (t < MBT) bs[t] = bias[t];
    __syncthreads();

    const int tc = t % CG;
    const int r0 = (t / CG) * RT;
    const int c0 = tc * 4;
    float4 acc[CS][RT];
#pragma unroll
    for (int s = 0; s < CS; s++)
#pragma unroll
        for (int r = 0; r < RT; r++) acc[s][r] = {0.f, 0.f, 0.f, 0.f};

#pragma unroll 4
    for (int k = 0; k < K; k += 4) {
        float4 w[CS][4];
#pragma unroll
        for (int s = 0; s < CS; s++) {
#pragma unroll
            for (int i = 0; i < 4; i++) {
                if (WLDS)
                    w[s][i] = *(const float4*)&Ws[(k + i) * MBT + s * MB + c0];
                else
                    w[s][i] = *(const float4*)&W[(size_t)(k + i) * MBT + s * MB + c0];
            }
        }
#pragma unroll
        for (int r = 0; r < RT; r++) {
            float4 av = *(const float4*)&As[(r0 + r) * KP + k];
#pragma unroll
            for (int s = 0; s < CS; s++) {
                acc[s][r].x += av.x * w[s][0].x + av.y * w[s][1].x + av.z * w[s][2].x + av.w * w[s][3].x;
                acc[s][r].y += av.x * w[s][0].y + av.y * w[s][1].y + av.z * w[s][2].y + av.w * w[s][3].y;
                acc[s][r].z += av.x * w[s][0].z + av.y * w[s][1].z + av.z * w[s][2].z + av.w * w[s][3].z;
                acc[s][r].w += av.x * w[s][0].w + av.y * w[s][1].w + av.z * w[s][2].w + av.w * w[s][3].w;
            }
        }
    }
#pragma unroll
    for (int r = 0; r < RT; r++) {
        int row = base + r0 + r;
        if (row < N) {
            float dd = PRESCALE ? dinv[row] : 1.f;
#pragma unroll
            for (int s = 0; s < CS; s++) {
                float4 v = acc[s][r];
                float4 bv = *(const float4*)&bs[s * MB + c0];
                v.x = fmaxf(v.x + bv.x, 0.f) * dd;
                v.y = fmaxf(v.y + bv.y, 0.f) * dd;
                v.z = fmaxf(v.z + bv.z, 0.f) * dd;
                v.w = fmaxf(v.w + bv.w, 0.f) * dd;
                ushort4 u;
                u.x = f_to_bf(v.x); u.y = f_to_bf(v.y);
                u.z = f_to_bf(v.z); u.w = f_to_bf(v.w);
                *(ushort4*)&out[(size_t)row * MBT + s * MB + c0] = u;
            }
        }
    }
}

// --- register-tiled GEMM (L1 only: fp32 x in, prescaled bf16 out) -----------
template<int K, int M, int MB, int RT, bool BIAS_RELU, bool PRESCALE, bool INBF, bool OUTBF>
__global__ __launch_bounds__(256) void gemm_kernel(
        const void* __restrict__ Av, const float* __restrict__ W,
        const float* __restrict__ bias, const float* __restrict__ dinv,
        void* __restrict__ outv, int N) {
    constexpr int CG = MB / 4;
    constexpr int TM = (256 / CG) * RT;
    constexpr int KP = K + 4;
    constexpr int MSPLIT = M / MB;
    static_assert(TM == 64, "tile rows");
    __shared__ float As[TM * KP];
    __shared__ float Ws[K * MB];
    __shared__ float bs[MB];
    const int t = threadIdx.x;
    const int base = (blockIdx.x / MSPLIT) * TM;
    const int colb = (blockIdx.x % MSPLIT) * MB;
    const int rows_valid = min(TM, N - base);
    if (INBF) {
        constexpr int KD8 = K / 8;
        const unsigned short* A = (const unsigned short*)Av;
        for (int idx = t; idx < TM * KD8; idx += 256) {
            int row = idx / KD8, kc = idx % KD8;
            if (row < rows_valid) {
                ushort8v u = *(const ushort8v*)&A[(size_t)(base + row) * K + kc * 8];
                float4 lo = {bf_to_f(u[0]), bf_to_f(u[1]), bf_to_f(u[2]), bf_to_f(u[3])};
                float4 hi = {bf_to_f(u[4]), bf_to_f(u[5]), bf_to_f(u[6]), bf_to_f(u[7])};
                *(float4*)&As[row * KP + kc * 8] = lo;
                *(float4*)&As[row * KP + kc * 8 + 4] = hi;
            }
        }
    } else {
        constexpr int KD4 = K / 4;
        const float* A = (const float*)Av;
        for (int idx = t; idx < TM * KD4; idx += 256) {
            int row = idx / KD4, kc = idx % KD4;
            if (row < rows_valid)
                *(float4*)&As[row * KP + kc * 4] = *(const float4*)&A[(size_t)(base + row) * K + kc * 4];
        }
    }
    constexpr int MD4 = MB / 4;
    for (int idx = t; idx < K * MD4; idx += 256) {
        int k = idx / MD4, c4 = idx % MD4;
        *(float4*)&Ws[k * MB + c4 * 4] = *(const float4*)&W[(size_t)k * M + colb + c4 * 4];
    }
    if (BIAS_RELU && t < MB) bs[t] = bias[colb + t];
    __syncthreads();

    const int tc = t % CG;
    const int r0 = (t / CG) * RT;
    const int c0 = tc * 4;
    float4 acc[RT];
#pragma unroll
    for (int r = 0; r < RT; r++) acc[r] = {0.f, 0.f, 0.f, 0.f};

#pragma unroll 4
    for (int k = 0; k < K; k += 4) {
        float4 w0 = *(const float4*)&Ws[(k + 0) * MB + c0];
        float4 w1 = *(const float4*)&Ws[(k + 1) * MB + c0];
        float4 w2 = *(const float4*)&Ws[(k + 2) * MB + c0];
        float4 w3 = *(const float4*)&Ws[(k + 3) * MB + c0];
#pragma unroll
        for (int r = 0; r < RT; r++) {
            float4 av = *(const float4*)&As[(r0 + r) * KP + k];
            acc[r].x += av.x * w0.x + av.y * w1.x + av.z * w2.x + av.w * w3.x;
            acc[r].y += av.x * w0.y + av.y * w1.y + av.z * w2.y + av.w * w3.y;
            acc[r].z += av.x * w0.z + av.y * w1.z + av.z * w2.z + av.w * w3.z;
            acc[r].w += av.x * w0.w + av.y * w1.w + av.z * w2.w + av.w * w3.w;
        }
    }
#pragma unroll
    for (int r = 0; r < RT; r++) {
        int row = base + r0 + r;
        if (row < N) {
            float4 v = acc[r];
            if (BIAS_RELU) {
                float4 bv = *(const float4*)&bs[c0];
                v.x = fmaxf(v.x + bv.x, 0.f); v.y = fmaxf(v.y + bv.y, 0.f);
                v.z = fmaxf(v.z + bv.z, 0.f); v.w = fmaxf(v.w + bv.w, 0.f);
            }
            if (PRESCALE) {
                float d = dinv[row];
                v.x *= d; v.y *= d; v.z *= d; v.w *= d;
            }
            if (OUTBF) {
                ushort4 u;
                u.x = f_to_bf(v.x); u.y = f_to_bf(v.y);
                u.z = f_to_bf(v.z); u.w = f_to_bf(v.w);
                *(ushort4*)&((unsigned short*)outv)[(size_t)row * M + colb + c0] = u;
            } else {
                *(float4*)&((float*)outv)[(size_t)row * M + colb + c0] = v;
            }
        }
    }
}

// --- fused FC head: h5 = relu(h4 @ Wf1 + bf1); out = tanh(h5 @ Wf2 + bf2) ---
__global__ __launch_bounds__(256) void head_kernel(
        const unsigned short* __restrict__ A, const float* __restrict__ Wf1,
        const float* __restrict__ bf1, const float* __restrict__ Wf2,
        const float* __restrict__ bf2, float* __restrict__ out, int N) {
    constexpr int K = 128, MB = 32, RT = 2, CG = 8, TM = 64, KP = K + 4;
    __shared__ float As[TM * KP];        // reused as h5 tile after k-loop
    __shared__ float Ws[K * MB];
    __shared__ float bs[MB];
    __shared__ float wt2[10 * 32];       // Wf2 transposed: wt2[m*32+k]
    __shared__ float bs2[10];
    const int t = threadIdx.x;
    const int base = blockIdx.x * TM;
    const int rows_valid = min(TM, N - base);
    constexpr int KD8 = K / 8;
    for (int idx = t; idx < TM * KD8; idx += 256) {
        int row = idx / KD8, kc = idx % KD8;
        if (row < rows_valid) {
            ushort8v u = *(const ushort8v*)&A[(size_t)(base + row) * K + kc * 8];
            float4 lo = {bf_to_f(u[0]), bf_to_f(u[1]), bf_to_f(u[2]), bf_to_f(u[3])};
            float4 hi = {bf_to_f(u[4]), bf_to_f(u[5]), bf_to_f(u[6]), bf_to_f(u[7])};
            *(float4*)&As[row * KP + kc * 8] = lo;
            *(float4*)&As[row * KP + kc * 8 + 4] = hi;
        }
    }
    for (int idx = t; idx < K * MB / 4; idx += 256) {
        int k = idx / (MB / 4), c4 = idx % (MB / 4);
        *(float4*)&Ws[k * MB + c4 * 4] = *(const float4*)&Wf1[(size_t)k * MB + c4 * 4];
    }
    if (t < MB) bs[t] = bf1[t];
    for (int idx = t; idx < 320; idx += 256)                 // strided staging
        wt2[(idx % 10) * 32 + idx / 10] = Wf2[idx];
    if (t < 10) bs2[t] = bf2[t];
    __syncthreads();

    const int tc = t % CG;
    const int r0 = (t / CG) * RT;
    const int c0 = tc * 4;
    float4 acc[RT];
#pragma unroll
    for (int r = 0; r < RT; r++) acc[r] = {0.f, 0.f, 0.f, 0.f};
#pragma unroll 4
    for (int k = 0; k < K; k += 4) {
        float4 w0 = *(const float4*)&Ws[(k + 0) * MB + c0];
        float4 w1 = *(const float4*)&Ws[(k + 1) * MB + c0];
        float4 w2 = *(const float4*)&Ws[(k + 2) * MB + c0];
        float4 w3 = *(const float4*)&Ws[(k + 3) * MB + c0];
#pragma unroll
        for (int r = 0; r < RT; r++) {
            float4 av = *(const float4*)&As[(r0 + r) * KP + k];
            acc[r].x += av.x * w0.x + av.y * w1.x + av.z * w2.x + av.w * w3.x;
            acc[r].y += av.x * w0.y + av.y * w1.y + av.z * w2.y + av.w * w3.y;
            acc[r].z += av.x * w0.z + av.y * w1.z + av.z * w2.z + av.w * w3.z;
            acc[r].w += av.x * w0.w + av.y * w1.w + av.z * w2.w + av.w * w3.w;
        }
    }
    __syncthreads();                     // all As reads done -> safe to alias
    float* h5s = As;                     // 64 x 32 tile, stride 33
#pragma unroll
    for (int r = 0; r < RT; r++) {
        int row = r0 + r;
        float4 bv = *(const float4*)&bs[c0];
        h5s[row * 33 + c0 + 0] = fmaxf(acc[r].x + bv.x, 0.f);
        h5s[row * 33 + c0 + 1] = fmaxf(acc[r].y + bv.y, 0.f);
        h5s[row * 33 + c0 + 2] = fmaxf(acc[r].z + bv.z, 0.f);
        h5s[row * 33 + c0 + 3] = fmaxf(acc[r].w + bv.w, 0.f);
    }
    __syncthreads();
    const int lrow = t >> 2;             // 0..63
    const int q = t & 3;
    const int grow = base + lrow;
    if (grow < N) {
        for (int m = q; m < 10; m += 4) {
            float a = bs2[m];
#pragma unroll
            for (int k = 0; k < 32; k++) a += h5s[lrow * 33 + k] * wt2[m * 32 + k];
            out[(size_t)grow * 10 + m] = tanhf(a);
        }
    }
}

extern "C" void kernel_launch(void* const* d_in, const int* in_sizes, int n_in,
                              void* d_out, int out_size, void* d_ws, size_t ws_size,
                              hipStream_t stream) {
    const float* x   = (const float*)d_in[0];
    const int*   ei  = (const int*)d_in[1];     // int32 on device
    const float* W1  = (const float*)d_in[2];
    const float* b1  = (const float*)d_in[3];
    const float* W2  = (const float*)d_in[4];
    const float* b2  = (const float*)d_in[5];
    const float* W3  = (const float*)d_in[6];
    const float* b3  = (const float*)d_in[7];
    const float* W4  = (const float*)d_in[8];
    const float* b4  = (const float*)d_in[9];
    const float* Wf1 = (const float*)d_in[10];
    const float* bf1 = (const float*)d_in[11];
    const float* Wf2 = (const float*)d_in[12];
    const float* bf2 = (const float*)d_in[13];

    const int N = in_sizes[0] / 128;   // 100000
    const int E = in_sizes[1] / 2;     // 1600000
    const int* e_src = ei;
    const int* e_dst = ei + E;

    char* p = (char*)d_ws;
    auto carve = [&](size_t bytes) -> void* {
        void* r = (void*)p;
        p += (bytes + 255) & ~(size_t)255;
        return r;
    };
    int*   bucket_cur = (int*)carve(512 * 4);
    float* dinv       = (float*)carve((size_t)N * 4);
    int*   row_ptr    = (int*)carve((size_t)N * 4);
    int*   degp       = (int*)carve((size_t)N * 4);
    int*   csr_tmp    = (int*)carve((size_t)NBUCK * BCAP * 4);
    int*   csr_src    = (int*)carve((size_t)NBUCK * BCAP * 4);
    unsigned short* bufP = (unsigned short*)carve((size_t)N * 128 * 2); // bf16 ping
    unsigned short* bufQ = (unsigned short*)carve((size_t)N * 128 * 2); // bf16 pong

    const int GB   = (N + 63) / 64;    // 1563 64-row blocks
    const int GB32 = (N + 31) / 32;    // 3125 32-row blocks
    const int AG16 = (N + 127) / 128;  // F=16 agg: 128 nodes/block

    // --- graph preprocessing: cursor init, place, bsort(+deg+dinv) ---
    init_cursor_kernel<<<2, 256, 0, stream>>>(bucket_cur);
    place_kernel<<<PREB, 256, 0, stream>>>(e_src, e_dst, bucket_cur, csr_tmp, E);
    bsort_kernel<<<NBUCK, 256, 0, stream>>>(bucket_cur, csr_tmp, row_ptr, csr_src, degp, dinv, N);

    // --- L1 (128->16): prescaled GEMM -> bf16 z1; standalone agg (bias+relu)
    gemm_kernel<128, 16, 16, 1, false, true, false, true><<<GB, 256, 0, stream>>>(
        x, W1, nullptr, dinv, bufP, N);
    agg_gpn_kernel<16, true, true><<<AG16, 256, 0, stream>>>(
        bufP, row_ptr, degp, csr_src, dinv, b1, bufQ, N);

    // --- L2 (16->32): fused agg+GEMM -> bf16 z2 (prescaled), TM=64 ---
    gemm_agg_kernel<16, 32, 2, 1, 4, true, true, 8><<<GB, 256, 0, stream>>>(
        bufQ, row_ptr, degp, csr_src, dinv, W2, b2, bufP, N);

    // --- L3 (32->64): fused agg+GEMM, TM=32 (2x grid), CPL=4 -> bf16 z3 ---
    gemm_agg_kernel<32, 64, 2, 1, 4, true, true, 8><<<GB32, 256, 0, stream>>>(
        bufP, row_ptr, degp, csr_src, dinv, W3, b3, bufQ, N);

    // --- L4 (64->128): fused agg+GEMM, TM=32, CS=2, W from global ---
    gemm_agg_kernel<64, 64, 2, 2, 8, false, false, 8><<<GB32, 256, 0, stream>>>(
        bufQ, row_ptr, degp, csr_src, dinv, W4, b4, bufP, N);

    // --- fused FC head: relu(h4 Wf1 + bf1) -> tanh(. Wf2 + bf2) ---
    head_kernel<<<GB, 256, 0, stream>>>(bufP, Wf1, bf1, Wf2, bf2, (float*)d_out, N);
}

// Round 6
// 321.282 us; speedup vs baseline: 1.0308x; 1.0308x over previous
//
#include <hip/hip_runtime.h>
#include <hip/hip_bf16.h>
#include <cmath>

// ---------------------------------------------------------------------------
// GCN: out = tanh(relu(relu(relu(relu(P(P(P(P(xW1+..)..) .. ))Wf1+bf1)Wf2+bf2
// P = D^-1/2 (A+I) D^-1/2 via bucketed CSR gather-sum, no float atomics.
// R14: group-per-node register agg (345.7us). R15: fixed-cap buckets + fused
// agg+GEMM (342.4). R16: L4 W global + U=8 (319.9, best). R17: TM=32 fused
// REGRESSED (331.2, L4 82.8us, occupancy FELL) -> occupancy isn't LDS/grid-
// limited; the fused barrier structure itself caps the L4 gather.
// R18: revert to R16 geometry; UNFUSE L4 only. Standalone agg_gpn<64> (no
// LDS, no barriers, U=8 in flight, 3125 blocks) + R14's M-split GEMM.
// Fusion stays for L2/L3 (L2-resident gathers, where it won in R15).
// ---------------------------------------------------------------------------

#define NBUCK 391              // ceil(100000/256) 256-node buckets
#define PREB  391              // ceil(E/4096) edge-phase blocks
#define BCAP  5120             // edges per bucket capacity (mean 4096, 16s)

typedef __attribute__((ext_vector_type(8))) unsigned short ushort8v;

__device__ __forceinline__ unsigned short f_to_bf(float v) {
    unsigned u = __float_as_uint(v);
    return (unsigned short)((u + 0x7FFF + ((u >> 16) & 1)) >> 16);   // RTN-even
}
__device__ __forceinline__ float bf_to_f(unsigned short v) {
    return __uint_as_float((unsigned)v << 16);
}

template<int VE> struct BFV;
template<> struct BFV<4> {
    using T = ushort4;
    __device__ static inline void unpack(const T& u, float* f) {
        f[0] = bf_to_f(u.x); f[1] = bf_to_f(u.y);
        f[2] = bf_to_f(u.z); f[3] = bf_to_f(u.w);
    }
};
template<> struct BFV<8> {
    using T = ushort8v;
    __device__ static inline void unpack(const T& u, float* f) {
#pragma unroll
        for (int j = 0; j < 8; j++) f[j] = bf_to_f(u[j]);
    }
};

__device__ __forceinline__ ushort8v pack8(const float* f) {
    ushort8v u;
#pragma unroll
    for (int j = 0; j < 8; j++) u[j] = f_to_bf(f[j]);
    return u;
}

__global__ void init_cursor_kernel(int* __restrict__ cur) {
    int i = blockIdx.x * 256 + threadIdx.x;
    if (i < NBUCK) cur[i] = i * BCAP;
}

// Phase A: scatter packed edges into fixed-capacity bucket regions.
// payload = (dst&255)<<17 | src. cursors pre-init'ed to b*BCAP.
__global__ __launch_bounds__(256) void place_kernel(
        const int* __restrict__ src, const int* __restrict__ dst,
        int* __restrict__ bucket_cursor, int* __restrict__ csr_tmp, int E) {
    __shared__ int hist[NBUCK];
    const int t = threadIdx.x;
    for (int i = t; i < NBUCK; i += 256) hist[i] = 0;
    __syncthreads();
    const int base = blockIdx.x * 4096;
    int pay[16], rb[16];
#pragma unroll
    for (int j = 0; j < 16; j++) {
        int e = base + j * 256 + t;
        if (e < E) {
            int d = dst[e];
            int b = d >> 8;
            int r = atomicAdd(&hist[b], 1);       // r < 4096 (12 bits)
            pay[j] = ((d & 255) << 17) | src[e];
            rb[j] = (r << 9) | b;                 // b < 512 (9 bits)
        } else rb[j] = -1;
    }
    __syncthreads();
    for (int i = t; i < NBUCK; i += 256) {
        int h = hist[i];
        hist[i] = h ? atomicAdd(&bucket_cursor[i], h) : 0;
    }
    __syncthreads();
#pragma unroll
    for (int j = 0; j < 16; j++) {
        if (rb[j] >= 0) {
            int b = rb[j] & 511;
            int r = rb[j] >> 9;
            csr_tmp[hist[b] + r] = pay[j];
        }
    }
}

// Phase B: one block per bucket -> per-node CSR (row_ptr + deg + csr_src,
// padded-bucket layout) + dinv.
__global__ __launch_bounds__(256) void bsort_kernel(
        const int* __restrict__ bucket_cursor, const int* __restrict__ csr_tmp,
        int* __restrict__ row_ptr, int* __restrict__ csr_src,
        int* __restrict__ degp, float* __restrict__ dinv, int N) {
    __shared__ int c[256], s[256], cur[256];
    const int b = blockIdx.x;
    const int t = threadIdx.x;
    const int start = b * BCAP;
    const int end = bucket_cursor[b];            // absolute fill end
    c[t] = 0;
    __syncthreads();
    for (int e = start + t; e < end; e += 256)
        atomicAdd(&c[csr_tmp[e] >> 17], 1);
    __syncthreads();
    int v = c[t];
    s[t] = v; __syncthreads();
    for (int off = 1; off < 256; off <<= 1) {
        int x = (t >= off) ? s[t - off] : 0;
        __syncthreads();
        s[t] += x;
        __syncthreads();
    }
    int excl = s[t] - v;
    int node = (b << 8) + t;
    if (node < N) {
        row_ptr[node] = start + excl;
        degp[node] = v;
        dinv[node] = rsqrtf((float)v + 1.0f);
    }
    cur[t] = start + excl;
    __syncthreads();
    for (int e = start + t; e < end; e += 256) {
        int p = csr_tmp[e];
        int pos = atomicAdd(&cur[p >> 17], 1);
        csr_src[pos] = p & 0x1FFFF;
    }
}

// --- group-per-node bf16 aggregation over PRESCALED input zs = dinv*z ------
// G = F/8 lanes own one node; 8 channels/lane in registers. U = gathers in
// flight per lane. No LDS, no barriers, no atomics. out[i] = dinv[i]*
// (sum_e zs[src_e] + zs[i]); optional bias+relu (L1MODE), output prescale.
template<int F, bool L1MODE, bool PRESCALE_OUT, int U>
__global__ __launch_bounds__(256) void agg_gpn_kernel(
        const unsigned short* __restrict__ z, const int* __restrict__ row_ptr,
        const int* __restrict__ degp, const int* __restrict__ csr_src,
        const float* __restrict__ dinv, const float* __restrict__ bias,
        unsigned short* __restrict__ out, int N) {
    constexpr int G  = F / 8;          // lanes per node
    constexpr int NPB = 256 / G;       // nodes per block
    const int t = threadIdx.x;
    const int c0 = (t % G) * 8;
    const int node = blockIdx.x * NPB + t / G;
    if (node >= N) return;             // group-uniform exit, no barriers below
    const int start = row_ptr[node];
    const int end   = start + degp[node];
    float acc[8];
#pragma unroll
    for (int j = 0; j < 8; j++) acc[j] = 0.f;
    int e = start;
    if (U == 8) {
        while (e + 7 < end) {          // U=8: 8 independent gathers in flight
            int ss[8];
#pragma unroll
            for (int u = 0; u < 8; u++) ss[u] = csr_src[e + u];
            ushort8v uu[8];
#pragma unroll
            for (int u = 0; u < 8; u++)
                uu[u] = *(const ushort8v*)&z[(size_t)ss[u] * F + c0];
#pragma unroll
            for (int u = 0; u < 8; u++) {
                float f[8];
                BFV<8>::unpack(uu[u], f);
#pragma unroll
                for (int j = 0; j < 8; j++) acc[j] += f[j];
            }
            e += 8;
        }
    }
    while (e + 3 < end) {              // U=4
        int s0 = csr_src[e];
        int s1 = csr_src[e + 1];
        int s2 = csr_src[e + 2];
        int s3 = csr_src[e + 3];
        ushort8v u0 = *(const ushort8v*)&z[(size_t)s0 * F + c0];
        ushort8v u1 = *(const ushort8v*)&z[(size_t)s1 * F + c0];
        ushort8v u2 = *(const ushort8v*)&z[(size_t)s2 * F + c0];
        ushort8v u3 = *(const ushort8v*)&z[(size_t)s3 * F + c0];
        float f0[8], f1[8], f2[8], f3[8];
        BFV<8>::unpack(u0, f0); BFV<8>::unpack(u1, f1);
        BFV<8>::unpack(u2, f2); BFV<8>::unpack(u3, f3);
#pragma unroll
        for (int j = 0; j < 8; j++) acc[j] += (f0[j] + f1[j]) + (f2[j] + f3[j]);
        e += 4;
    }
    if (e + 1 < end) {                 // U=2
        int s0 = csr_src[e];
        int s1 = csr_src[e + 1];
        ushort8v u0 = *(const ushort8v*)&z[(size_t)s0 * F + c0];
        ushort8v u1 = *(const ushort8v*)&z[(size_t)s1 * F + c0];
        float f0[8], f1[8];
        BFV<8>::unpack(u0, f0); BFV<8>::unpack(u1, f1);
#pragma unroll
        for (int j = 0; j < 8; j++) acc[j] += f0[j] + f1[j];
        e += 2;
    }
    if (e < end) {                     // tail
        int s0 = csr_src[e];
        ushort8v u0 = *(const ushort8v*)&z[(size_t)s0 * F + c0];
        float f0[8];
        BFV<8>::unpack(u0, f0);
#pragma unroll
        for (int j = 0; j < 8; j++) acc[j] += f0[j];
    }
    const float di = dinv[node];
    ushort8v us = *(const ushort8v*)&z[(size_t)node * F + c0];
    float fs[8], r[8];
    BFV<8>::unpack(us, fs);
#pragma unroll
    for (int j = 0; j < 8; j++) r[j] = di * (acc[j] + fs[j]);
    if (L1MODE) {
#pragma unroll
        for (int j = 0; j < 8; j++) r[j] = fmaxf(r[j] + bias[c0 + j], 0.f);
    }
    if (PRESCALE_OUT) {
#pragma unroll
        for (int j = 0; j < 8; j++) r[j] *= di;
    }
    *(ushort8v*)&out[(size_t)node * F + c0] = pack8(r);
}

// --- fused agg+GEMM (L2/L3): As[r][k] = dinv*(sum_e z[src][k] + z[r][k]);
// out = relu(As @ W + b) * dinv, bf16 out, width MB*CS. CPL channels/lane in
// gather; WLDS=false reads W from global. U = gathers in flight per lane.
template<int K, int MB, int RT, int CS, int CPL, bool PRESCALE, bool WLDS, int U>
__global__ __launch_bounds__(256) void gemm_agg_kernel(
        const unsigned short* __restrict__ z, const int* __restrict__ row_ptr,
        const int* __restrict__ degp, const int* __restrict__ csr_src,
        const float* __restrict__ dinv, const float* __restrict__ W,
        const float* __restrict__ bias, unsigned short* __restrict__ out, int N) {
    constexpr int CG = MB / 4;
    constexpr int TM = (256 / CG) * RT;
    constexpr int KP = K + 4;            // 2-way bank alias on As reads (free)
    constexpr int MBT = MB * CS;
    static_assert(TM == 64, "tile rows");
    __shared__ float As[TM * KP];
    __shared__ float Ws[WLDS ? K * MBT : 4];
    __shared__ float bs[MBT];
    const int t = threadIdx.x;
    const int base = blockIdx.x * TM;

    {   // ---- gather-staged A (the fused aggregation) ----
        using VT = typename BFV<CPL>::T;
        constexpr int G = K / CPL;       // lanes per node
        constexpr int NPB = 256 / G;     // nodes in flight
        const int gg = t / G;
        const int ac0 = (t % G) * CPL;
        for (int r = gg; r < TM; r += NPB) {
            const int node = base + r;
            float res[CPL];
            if (node < N) {
                const int start = row_ptr[node];
                const int end = start + degp[node];
                float acc[CPL];
#pragma unroll
                for (int j = 0; j < CPL; j++) acc[j] = 0.f;
                int e = start;
                if (U == 8) {
                    while (e + 7 < end) {    // U=8 gathers in flight
                        int ss[8];
#pragma unroll
                        for (int u = 0; u < 8; u++) ss[u] = csr_src[e + u];
                        VT uu[8];
#pragma unroll
                        for (int u = 0; u < 8; u++)
                            uu[u] = *(const VT*)&z[(size_t)ss[u] * K + ac0];
#pragma unroll
                        for (int u = 0; u < 8; u++) {
                            float f[CPL];
                            BFV<CPL>::unpack(uu[u], f);
#pragma unroll
                            for (int j = 0; j < CPL; j++) acc[j] += f[j];
                        }
                        e += 8;
                    }
                }
                while (e + 3 < end) {    // U=4 gathers in flight
                    int s0 = csr_src[e];
                    int s1 = csr_src[e + 1];
                    int s2 = csr_src[e + 2];
                    int s3 = csr_src[e + 3];
                    VT u0 = *(const VT*)&z[(size_t)s0 * K + ac0];
                    VT u1 = *(const VT*)&z[(size_t)s1 * K + ac0];
                    VT u2 = *(const VT*)&z[(size_t)s2 * K + ac0];
                    VT u3 = *(const VT*)&z[(size_t)s3 * K + ac0];
                    float f0[CPL], f1[CPL], f2[CPL], f3[CPL];
                    BFV<CPL>::unpack(u0, f0); BFV<CPL>::unpack(u1, f1);
                    BFV<CPL>::unpack(u2, f2); BFV<CPL>::unpack(u3, f3);
#pragma unroll
                    for (int j = 0; j < CPL; j++)
                        acc[j] += (f0[j] + f1[j]) + (f2[j] + f3[j]);
                    e += 4;
                }
                if (e + 1 < end) {       // U=2
                    int s0 = csr_src[e];
                    int s1 = csr_src[e + 1];
                    VT u0 = *(const VT*)&z[(size_t)s0 * K + ac0];
                    VT u1 = *(const VT*)&z[(size_t)s1 * K + ac0];
                    float f0[CPL], f1[CPL];
                    BFV<CPL>::unpack(u0, f0); BFV<CPL>::unpack(u1, f1);
#pragma unroll
                    for (int j = 0; j < CPL; j++) acc[j] += f0[j] + f1[j];
                    e += 2;
                }
                if (e < end) {           // tail
                    int s0 = csr_src[e];
                    VT u0 = *(const VT*)&z[(size_t)s0 * K + ac0];
                    float f0[CPL];
                    BFV<CPL>::unpack(u0, f0);
#pragma unroll
                    for (int j = 0; j < CPL; j++) acc[j] += f0[j];
                }
                const float di = dinv[node];
                VT us = *(const VT*)&z[(size_t)node * K + ac0];
                float fs[CPL];
                BFV<CPL>::unpack(us, fs);
#pragma unroll
                for (int j = 0; j < CPL; j++) res[j] = di * (acc[j] + fs[j]);
            } else {
#pragma unroll
                for (int j = 0; j < CPL; j++) res[j] = 0.f;
            }
#pragma unroll
            for (int j = 0; j < CPL; j++) As[r * KP + ac0 + j] = res[j];
        }
    }
    // ---- W (optional) + bias staging ----
    if (WLDS) {
        constexpr int MD4 = MBT / 4;
        for (int idx = t; idx < K * MD4; idx += 256) {
            int k = idx / MD4, c4 = idx % MD4;
            *(float4*)&Ws[k * MBT + c4 * 4] = *(const float4*)&W[(size_t)k * MBT + c4 * 4];
        }
    }
    if (t < MBT) bs[t] = bias[t];
    __syncthreads();

    const int tc = t % CG;
    const int r0 = (t / CG) * RT;
    const int c0 = tc * 4;
    float4 acc[CS][RT];
#pragma unroll
    for (int s = 0; s < CS; s++)
#pragma unroll
        for (int r = 0; r < RT; r++) acc[s][r] = {0.f, 0.f, 0.f, 0.f};

#pragma unroll 4
    for (int k = 0; k < K; k += 4) {
        float4 w[CS][4];
#pragma unroll
        for (int s = 0; s < CS; s++) {
#pragma unroll
            for (int i = 0; i < 4; i++) {
                if (WLDS)
                    w[s][i] = *(const float4*)&Ws[(k + i) * MBT + s * MB + c0];
                else
                    w[s][i] = *(const float4*)&W[(size_t)(k + i) * MBT + s * MB + c0];
            }
        }
#pragma unroll
        for (int r = 0; r < RT; r++) {
            float4 av = *(const float4*)&As[(r0 + r) * KP + k];
#pragma unroll
            for (int s = 0; s < CS; s++) {
                acc[s][r].x += av.x * w[s][0].x + av.y * w[s][1].x + av.z * w[s][2].x + av.w * w[s][3].x;
                acc[s][r].y += av.x * w[s][0].y + av.y * w[s][1].y + av.z * w[s][2].y + av.w * w[s][3].y;
                acc[s][r].z += av.x * w[s][0].z + av.y * w[s][1].z + av.z * w[s][2].z + av.w * w[s][3].z;
                acc[s][r].w += av.x * w[s][0].w + av.y * w[s][1].w + av.z * w[s][2].w + av.w * w[s][3].w;
            }
        }
    }
#pragma unroll
    for (int r = 0; r < RT; r++) {
        int row = base + r0 + r;
        if (row < N) {
            float dd = PRESCALE ? dinv[row] : 1.f;
#pragma unroll
            for (int s = 0; s < CS; s++) {
                float4 v = acc[s][r];
                float4 bv = *(const float4*)&bs[s * MB + c0];
                v.x = fmaxf(v.x + bv.x, 0.f) * dd;
                v.y = fmaxf(v.y + bv.y, 0.f) * dd;
                v.z = fmaxf(v.z + bv.z, 0.f) * dd;
                v.w = fmaxf(v.w + bv.w, 0.f) * dd;
                ushort4 u;
                u.x = f_to_bf(v.x); u.y = f_to_bf(v.y);
                u.z = f_to_bf(v.z); u.w = f_to_bf(v.w);
                *(ushort4*)&out[(size_t)row * MBT + s * MB + c0] = u;
            }
        }
    }
}

// --- register-tiled GEMM (L1 fp32-in; L4 bf16-in M-split) -------------------
template<int K, int M, int MB, int RT, bool BIAS_RELU, bool PRESCALE, bool INBF, bool OUTBF>
__global__ __launch_bounds__(256) void gemm_kernel(
        const void* __restrict__ Av, const float* __restrict__ W,
        const float* __restrict__ bias, const float* __restrict__ dinv,
        void* __restrict__ outv, int N) {
    constexpr int CG = MB / 4;
    constexpr int TM = (256 / CG) * RT;
    constexpr int KP = K + 4;
    constexpr int MSPLIT = M / MB;
    static_assert(TM == 64, "tile rows");
    __shared__ float As[TM * KP];
    __shared__ float Ws[K * MB];
    __shared__ float bs[MB];
    const int t = threadIdx.x;
    const int base = (blockIdx.x / MSPLIT) * TM;
    const int colb = (blockIdx.x % MSPLIT) * MB;
    const int rows_valid = min(TM, N - base);
    if (INBF) {
        constexpr int KD8 = K / 8;
        const unsigned short* A = (const unsigned short*)Av;
        for (int idx = t; idx < TM * KD8; idx += 256) {
            int row = idx / KD8, kc = idx % KD8;
            if (row < rows_valid) {
                ushort8v u = *(const ushort8v*)&A[(size_t)(base + row) * K + kc * 8];
                float4 lo = {bf_to_f(u[0]), bf_to_f(u[1]), bf_to_f(u[2]), bf_to_f(u[3])};
                float4 hi = {bf_to_f(u[4]), bf_to_f(u[5]), bf_to_f(u[6]), bf_to_f(u[7])};
                *(float4*)&As[row * KP + kc * 8] = lo;
                *(float4*)&As[row * KP + kc * 8 + 4] = hi;
            }
        }
    } else {
        constexpr int KD4 = K / 4;
        const float* A = (const float*)Av;
        for (int idx = t; idx < TM * KD4; idx += 256) {
            int row = idx / KD4, kc = idx % KD4;
            if (row < rows_valid)
                *(float4*)&As[row * KP + kc * 4] = *(const float4*)&A[(size_t)(base + row) * K + kc * 4];
        }
    }
    constexpr int MD4 = MB / 4;
    for (int idx = t; idx < K * MD4; idx += 256) {
        int k = idx / MD4, c4 = idx % MD4;
        *(float4*)&Ws[k * MB + c4 * 4] = *(const float4*)&W[(size_t)k * M + colb + c4 * 4];
    }
    if (BIAS_RELU && t < MB) bs[t] = bias[colb + t];
    __syncthreads();

    const int tc = t % CG;
    const int r0 = (t / CG) * RT;
    const int c0 = tc * 4;
    float4 acc[RT];
#pragma unroll
    for (int r = 0; r < RT; r++) acc[r] = {0.f, 0.f, 0.f, 0.f};

#pragma unroll 4
    for (int k = 0; k < K; k += 4) {
        float4 w0 = *(const float4*)&Ws[(k + 0) * MB + c0];
        float4 w1 = *(const float4*)&Ws[(k + 1) * MB + c0];
        float4 w2 = *(const float4*)&Ws[(k + 2) * MB + c0];
        float4 w3 = *(const float4*)&Ws[(k + 3) * MB + c0];
#pragma unroll
        for (int r = 0; r < RT; r++) {
            float4 av = *(const float4*)&As[(r0 + r) * KP + k];
            acc[r].x += av.x * w0.x + av.y * w1.x + av.z * w2.x + av.w * w3.x;
            acc[r].y += av.x * w0.y + av.y * w1.y + av.z * w2.y + av.w * w3.y;
            acc[r].z += av.x * w0.z + av.y * w1.z + av.z * w2.z + av.w * w3.z;
            acc[r].w += av.x * w0.w + av.y * w1.w + av.z * w2.w + av.w * w3.w;
        }
    }
#pragma unroll
    for (int r = 0; r < RT; r++) {
        int row = base + r0 + r;
        if (row < N) {
            float4 v = acc[r];
            if (BIAS_RELU) {
                float4 bv = *(const float4*)&bs[c0];
                v.x = fmaxf(v.x + bv.x, 0.f); v.y = fmaxf(v.y + bv.y, 0.f);
                v.z = fmaxf(v.z + bv.z, 0.f); v.w = fmaxf(v.w + bv.w, 0.f);
            }
            if (PRESCALE) {
                float d = dinv[row];
                v.x *= d; v.y *= d; v.z *= d; v.w *= d;
            }
            if (OUTBF) {
                ushort4 u;
                u.x = f_to_bf(v.x); u.y = f_to_bf(v.y);
                u.z = f_to_bf(v.z); u.w = f_to_bf(v.w);
                *(ushort4*)&((unsigned short*)outv)[(size_t)row * M + colb + c0] = u;
            } else {
                *(float4*)&((float*)outv)[(size_t)row * M + colb + c0] = v;
            }
        }
    }
}

// --- fused FC head: h5 = relu(h4 @ Wf1 + bf1); out = tanh(h5 @ Wf2 + bf2) ---
__global__ __launch_bounds__(256) void head_kernel(
        const unsigned short* __restrict__ A, const float* __restrict__ Wf1,
        const float* __restrict__ bf1, const float* __restrict__ Wf2,
        const float* __restrict__ bf2, float* __restrict__ out, int N) {
    constexpr int K = 128, MB = 32, RT = 2, CG = 8, TM = 64, KP = K + 4;
    __shared__ float As[TM * KP];        // reused as h5 tile after k-loop
    __shared__ float Ws[K * MB];
    __shared__ float bs[MB];
    __shared__ float wt2[10 * 32];       // Wf2 transposed: wt2[m*32+k]
    __shared__ float bs2[10];
    const int t = threadIdx.x;
    const int base = blockIdx.x * TM;
    const int rows_valid = min(TM, N - base);
    constexpr int KD8 = K / 8;
    for (int idx = t; idx < TM * KD8; idx += 256) {
        int row = idx / KD8, kc = idx % KD8;
        if (row < rows_valid) {
            ushort8v u = *(const ushort8v*)&A[(size_t)(base + row) * K + kc * 8];
            float4 lo = {bf_to_f(u[0]), bf_to_f(u[1]), bf_to_f(u[2]), bf_to_f(u[3])};
            float4 hi = {bf_to_f(u[4]), bf_to_f(u[5]), bf_to_f(u[6]), bf_to_f(u[7])};
            *(float4*)&As[row * KP + kc * 8] = lo;
            *(float4*)&As[row * KP + kc * 8 + 4] = hi;
        }
    }
    for (int idx = t; idx < K * MB / 4; idx += 256) {
        int k = idx / (MB / 4), c4 = idx % (MB / 4);
        *(float4*)&Ws[k * MB + c4 * 4] = *(const float4*)&Wf1[(size_t)k * MB + c4 * 4];
    }
    if (t < MB) bs[t] = bf1[t];
    for (int idx = t; idx < 320; idx += 256)                 // strided staging
        wt2[(idx % 10) * 32 + idx / 10] = Wf2[idx];
    if (t < 10) bs2[t] = bf2[t];
    __syncthreads();

    const int tc = t % CG;
    const int r0 = (t / CG) * RT;
    const int c0 = tc * 4;
    float4 acc[RT];
#pragma unroll
    for (int r = 0; r < RT; r++) acc[r] = {0.f, 0.f, 0.f, 0.f};
#pragma unroll 4
    for (int k = 0; k < K; k += 4) {
        float4 w0 = *(const float4*)&Ws[(k + 0) * MB + c0];
        float4 w1 = *(const float4*)&Ws[(k + 1) * MB + c0];
        float4 w2 = *(const float4*)&Ws[(k + 2) * MB + c0];
        float4 w3 = *(const float4*)&Ws[(k + 3) * MB + c0];
#pragma unroll
        for (int r = 0; r < RT; r++) {
            float4 av = *(const float4*)&As[(r0 + r) * KP + k];
            acc[r].x += av.x * w0.x + av.y * w1.x + av.z * w2.x + av.w * w3.x;
            acc[r].y += av.x * w0.y + av.y * w1.y + av.z * w2.y + av.w * w3.y;
            acc[r].z += av.x * w0.z + av.y * w1.z + av.z * w2.z + av.w * w3.z;
            acc[r].w += av.x * w0.w + av.y * w1.w + av.z * w2.w + av.w * w3.w;
        }
    }
    __syncthreads();                     // all As reads done -> safe to alias
    float* h5s = As;                     // 64 x 32 tile, stride 33
#pragma unroll
    for (int r = 0; r < RT; r++) {
        int row = r0 + r;
        float4 bv = *(const float4*)&bs[c0];
        h5s[row * 33 + c0 + 0] = fmaxf(acc[r].x + bv.x, 0.f);
        h5s[row * 33 + c0 + 1] = fmaxf(acc[r].y + bv.y, 0.f);
        h5s[row * 33 + c0 + 2] = fmaxf(acc[r].z + bv.z, 0.f);
        h5s[row * 33 + c0 + 3] = fmaxf(acc[r].w + bv.w, 0.f);
    }
    __syncthreads();
    const int lrow = t >> 2;             // 0..63
    const int q = t & 3;
    const int grow = base + lrow;
    if (grow < N) {
        for (int m = q; m < 10; m += 4) {
            float a = bs2[m];
#pragma unroll
            for (int k = 0; k < 32; k++) a += h5s[lrow * 33 + k] * wt2[m * 32 + k];
            out[(size_t)grow * 10 + m] = tanhf(a);
        }
    }
}

extern "C" void kernel_launch(void* const* d_in, const int* in_sizes, int n_in,
                              void* d_out, int out_size, void* d_ws, size_t ws_size,
                              hipStream_t stream) {
    const float* x   = (const float*)d_in[0];
    const int*   ei  = (const int*)d_in[1];     // int32 on device
    const float* W1  = (const float*)d_in[2];
    const float* b1  = (const float*)d_in[3];
    const float* W2  = (const float*)d_in[4];
    const float* b2  = (const float*)d_in[5];
    const float* W3  = (const float*)d_in[6];
    const float* b3  = (const float*)d_in[7];
    const float* W4  = (const float*)d_in[8];
    const float* b4  = (const float*)d_in[9];
    const float* Wf1 = (const float*)d_in[10];
    const float* bf1 = (const float*)d_in[11];
    const float* Wf2 = (const float*)d_in[12];
    const float* bf2 = (const float*)d_in[13];

    const int N = in_sizes[0] / 128;   // 100000
    const int E = in_sizes[1] / 2;     // 1600000
    const int* e_src = ei;
    const int* e_dst = ei + E;

    char* p = (char*)d_ws;
    auto carve = [&](size_t bytes) -> void* {
        void* r = (void*)p;
        p += (bytes + 255) & ~(size_t)255;
        return r;
    };
    int*   bucket_cur = (int*)carve(512 * 4);
    float* dinv       = (float*)carve((size_t)N * 4);
    int*   row_ptr    = (int*)carve((size_t)N * 4);
    int*   degp       = (int*)carve((size_t)N * 4);
    int*   csr_tmp    = (int*)carve((size_t)NBUCK * BCAP * 4);
    int*   csr_src    = (int*)carve((size_t)NBUCK * BCAP * 4);
    unsigned short* bufP = (unsigned short*)carve((size_t)N * 128 * 2); // bf16 ping
    unsigned short* bufQ = (unsigned short*)carve((size_t)N * 128 * 2); // bf16 pong

    const int GB   = (N + 63) / 64;    // 1563 64-row blocks
    const int AG16 = (N + 127) / 128;  // F=16 agg: 128 nodes/block
    const int AG64 = (N + 31) / 32;    // F=64 agg: 32 nodes/block (3125)

    // --- graph preprocessing: cursor init, place, bsort(+deg+dinv) ---
    init_cursor_kernel<<<2, 256, 0, stream>>>(bucket_cur);
    place_kernel<<<PREB, 256, 0, stream>>>(e_src, e_dst, bucket_cur, csr_tmp, E);
    bsort_kernel<<<NBUCK, 256, 0, stream>>>(bucket_cur, csr_tmp, row_ptr, csr_src, degp, dinv, N);

    // --- L1 (128->16): prescaled GEMM -> bf16 z1; standalone agg (bias+relu)
    gemm_kernel<128, 16, 16, 1, false, true, false, true><<<GB, 256, 0, stream>>>(
        x, W1, nullptr, dinv, bufP, N);
    agg_gpn_kernel<16, true, true, 4><<<AG16, 256, 0, stream>>>(
        bufP, row_ptr, degp, csr_src, dinv, b1, bufQ, N);

    // --- L2 (16->32): fused agg+GEMM -> bf16 z2 (prescaled), TM=64 ---
    gemm_agg_kernel<16, 32, 2, 1, 4, true, true, 8><<<GB, 256, 0, stream>>>(
        bufQ, row_ptr, degp, csr_src, dinv, W2, b2, bufP, N);

    // --- L3 (32->64): fused agg+GEMM, TM=64, CPL=8 (R16 best config) ---
    gemm_agg_kernel<32, 64, 4, 1, 8, true, true, 8><<<GB, 256, 0, stream>>>(
        bufP, row_ptr, degp, csr_src, dinv, W3, b3, bufQ, N);

    // --- L4 (64->128): UNFUSED. high-TLP agg (U=8, no LDS/barriers), then
    // R14's M-split GEMM (bf16 in, bias+relu, bf16 out) ---
    agg_gpn_kernel<64, false, false, 8><<<AG64, 256, 0, stream>>>(
        bufQ, row_ptr, degp, csr_src, dinv, nullptr, bufP, N);
    gemm_kernel<64, 128, 64, 4, true, false, true, true><<<GB * 2, 256, 0, stream>>>(
        bufP, W4, b4, nullptr, bufQ, N);

    // --- fused FC head: relu(h4 Wf1 + bf1) -> tanh(. Wf2 + bf2) ---
    head_kernel<<<GB, 256, 0, stream>>>(bufQ, Wf1, bf1, Wf2, bf2, (float*)d_out, N);
}